// Round 1
// baseline (1680.025 us; speedup 1.0000x reference)
//
#include <hip/hip_runtime.h>
#include <math.h>

#define NB 8
#define NN 2048
#define NM 2048
#define NITERS 50

static constexpr float F_EPS  = 0.005f;
static constexpr float LOG2E  = 1.4426950408889634f;
static constexpr float KK     = LOG2E / F_EPS;      // 288.539008...
static constexpr float TWOK   = 2.0f * KK;
static constexpr float NEG_LOG2N = -11.0f;          // log2e * (-ln 2048) = -log2(2048)

__device__ __forceinline__ float fexp2(float x) { return __builtin_amdgcn_exp2f(x); }
__device__ __forceinline__ float flog2(float x) { return __builtin_amdgcn_logf(x); }

// ---------------------------------------------------------------------------
// Pack kernel: P[i] = (v0, v1, v2, K*(dual - |v|^2)) with dual = 0.
// ---------------------------------------------------------------------------
__global__ void pack_init(const float* __restrict__ V, float4* __restrict__ Pout, int total)
{
    int i = blockIdx.x * blockDim.x + threadIdx.x;
    if (i < total) {
        float v0 = V[3*i], v1 = V[3*i+1], v2 = V[3*i+2];
        float s  = fmaf(v0, v0, fmaf(v1, v1, v2*v2));
        Pout[i]  = make_float4(v0, v1, v2, -KK * s);
    }
}

// ---------------------------------------------------------------------------
// One Sinkhorn half-sweep.  Computes, for each row point v (this side),
//   dual = eps*(log_mu - logsumexp_m((dual_m - c(v, u_m))/eps))
// and writes the packed output (v0,v1,v2, K*(dual - |v|^2)).
//
// z (log2 domain) = (A_in[m] - K|v|^2) + 2K * (v . u_m)    -- 1 sub + 3 fma
//
// 8 waves per workgroup; wave w owns m-chunk [w*256, w*256+256), lane = row.
// Streaming chunked logsumexp with an 8-wide register z-buffer.
// ---------------------------------------------------------------------------
__global__ __launch_bounds__(512) void sink_update(
    const float4* __restrict__ Pin,   // [B][M] packed opposite side
    const float*  __restrict__ Vraw,  // [B][N][3] raw points of side being updated
    float4*       __restrict__ Pout)  // [B][N] packed output
{
    __shared__ float2 part[8][64];
    const int lane = threadIdx.x & 63;
    const int wave = threadIdx.x >> 6;
    const int wgs_per_b = NN / 64;                   // 32
    const int b   = blockIdx.x / wgs_per_b;
    const int row = (blockIdx.x % wgs_per_b) * 64 + lane;

    const float* vp = Vraw + ((size_t)(b * NN + row)) * 3;
    const float x0 = vp[0], x1 = vp[1], x2 = vp[2];
    const float xsq = fmaf(x0, x0, fmaf(x1, x1, x2 * x2));
    const float B0  = KK * xsq;
    const float xs0 = TWOK * x0, xs1 = TWOK * x1, xs2 = TWOK * x2;

    const int CH    = NM / 8;                        // 256 m's per wave
    const int mbase = __builtin_amdgcn_readfirstlane(b * NM + wave * CH);
    const float4* __restrict__ pp = Pin + mbase;

    float run_m = -1e30f, run_s = 0.f;
    for (int i = 0; i < CH; i += 8) {
        float z[8];
        #pragma unroll
        for (int j = 0; j < 8; ++j) {
            const float4 p = pp[i + j];
            z[j] = fmaf(xs0, p.x, fmaf(xs1, p.y, fmaf(xs2, p.z, p.w - B0)));
        }
        float c0 = fmaxf(fmaxf(z[0], z[1]), z[2]);
        float c1 = fmaxf(fmaxf(z[3], z[4]), z[5]);
        float c2 = fmaxf(z[6], z[7]);
        float cmax = fmaxf(fmaxf(c0, c1), c2);
        float nm = fmaxf(run_m, cmax);
        float s0 = fexp2(z[0] - nm) + fexp2(z[1] - nm);
        float s1 = fexp2(z[2] - nm) + fexp2(z[3] - nm);
        float s2 = fexp2(z[4] - nm) + fexp2(z[5] - nm);
        float s3 = fexp2(z[6] - nm) + fexp2(z[7] - nm);
        float s8 = (s0 + s1) + (s2 + s3);
        run_s = fmaf(run_s, fexp2(run_m - nm), s8);
        run_m = nm;
    }

    part[wave][lane] = make_float2(run_m, run_s);
    __syncthreads();

    if (threadIdx.x < 64) {   // wave 0: lane == row_local, has this row's x regs
        float gm = -1e30f;
        #pragma unroll
        for (int c = 0; c < 8; ++c) gm = fmaxf(gm, part[c][lane].x);
        float s = 0.f;
        #pragma unroll
        for (int c = 0; c < 8; ++c) s += part[c][lane].y * fexp2(part[c][lane].x - gm);
        const float lse2 = gm + flog2(s);            // log2 of row sum
        const float Aout = NEG_LOG2N - lse2 - B0;    // K*(dual - |v|^2)
        Pout[b * NN + row] = make_float4(x0, x1, x2, Aout);
    }
}

// ---------------------------------------------------------------------------
// Final loss: out = (1/B) * sum_{b,n,m} P*C,  P = exp2(Af + Ag + 2K*dot),
// C = max(|x|^2+|y|^2-2dot, 0).
// ---------------------------------------------------------------------------
__global__ __launch_bounds__(512) void final_loss(
    const float4* __restrict__ Px, const float4* __restrict__ Py,
    float* __restrict__ out)
{
    const int lane = threadIdx.x & 63;
    const int wave = threadIdx.x >> 6;
    const int wgs_per_b = NN / 64;
    const int b   = blockIdx.x / wgs_per_b;
    const int row = (blockIdx.x % wgs_per_b) * 64 + lane;

    const float4 xp = Px[b * NN + row];
    const float x0 = xp.x, x1 = xp.y, x2 = xp.z, Af = xp.w;
    const float xsq = fmaf(x0, x0, fmaf(x1, x1, x2 * x2));

    const int CH    = NM / 8;
    const int mbase = __builtin_amdgcn_readfirstlane(b * NM + wave * CH);
    const float4* __restrict__ pp = Py + mbase;

    float acc = 0.f;
    #pragma unroll 4
    for (int i = 0; i < CH; ++i) {
        const float4 p = pp[i];
        const float dot = fmaf(x0, p.x, fmaf(x1, p.y, x2 * p.z));
        const float ysq = fmaf(p.x, p.x, fmaf(p.y, p.y, p.z * p.z));
        float cc = fmaf(-2.f, dot, xsq + ysq);
        cc = fmaxf(cc, 0.f);
        const float zp = fmaf(TWOK, dot, Af + p.w);
        acc = fmaf(fexp2(zp), cc, acc);
    }
    #pragma unroll
    for (int o = 32; o > 0; o >>= 1) acc += __shfl_xor(acc, o);
    if (lane == 0) atomicAdd(out, acc * (1.0f / NB));
}

// ---------------------------------------------------------------------------
extern "C" void kernel_launch(void* const* d_in, const int* in_sizes, int n_in,
                              void* d_out, int out_size, void* d_ws, size_t ws_size,
                              hipStream_t stream)
{
    const float* x = (const float*)d_in[0];
    const float* y = (const float*)d_in[1];
    float4* Px = (float4*)d_ws;            // [B][N] packed x-side
    float4* Py = Px + NB * NN;             // [B][M] packed y-side

    // g = 0 initial pack of the y side
    pack_init<<<(NB * NM + 255) / 256, 256, 0, stream>>>(y, Py, NB * NM);

    for (int it = 0; it < NITERS; ++it) {
        sink_update<<<NB * NN / 64, 512, 0, stream>>>(Py, x, Px);  // f-update
        sink_update<<<NB * NM / 64, 512, 0, stream>>>(Px, y, Py);  // g-update
    }

    hipMemsetAsync(d_out, 0, sizeof(float), stream);
    final_loss<<<NB * NN / 64, 512, 0, stream>>>(Px, Py, (float*)d_out);
}